// Round 2
// baseline (5686.811 us; speedup 1.0000x reference)
//
#include <hip/hip_runtime.h>
#include <hip/hip_bf16.h>

// Problem constants (B=2, S=2048, HID=2048, NH=32, NKV=8, D=64, M=256, CHUNK=128)
#define SEQ   2048
#define NHEAD 32
#define NKVH  8
#define DH    64
#define MFEAT 256
#define NCH   16
#define EPSF  1e-6f

typedef __hip_bfloat16 bf16;

__device__ __forceinline__ float b2f(bf16 x){ return __bfloat162float(x); }
__device__ __forceinline__ bf16  f2b(float x){ return __float2bfloat16(x); }

// dtype probe: d_in[1] is cos; cos[0]==1.0 exactly.
// fp32 -> word0 = 0x3F800000 (low16==0). bf16-packed -> 0x3F803F80 (low16!=0).
__device__ __forceinline__ bool probe_f32(const unsigned* __restrict__ p){
  return (p[0] & 0xFFFFu) == 0u;
}
__device__ __forceinline__ float loadIn(const void* __restrict__ ptr, size_t idx, bool f32){
  return f32 ? ((const float*)ptr)[idx] : b2f(((const bf16*)ptr)[idx]);
}

// ---------------------------------------------------------------------------
// Generic GEMM: C[r,c] = sum_k A[r,k]*W[c,k].
// mode 0: out[r*N + c] (dtype follows probe: f32 or bf16)
// mode 1: outf[((b*H + c/64)*SEQ + s)*64 + (c%64)] fp32 head-major scatter
// aDyn: A follows input dtype (1) or is always internal bf16 (0).
// Tile 128x128, BK=32, 256 threads, 8x8 per thread (split 4+4 blocked).
// ---------------------------------------------------------------------------
__global__ __launch_bounds__(256) void gemm_bt(const void* __restrict__ A,
    const void* __restrict__ W, float* __restrict__ outf,
    void* __restrict__ outAny, int K, int N, int H, int mode, int aDyn,
    const unsigned* __restrict__ probe)
{
  const bool f32in = probe_f32(probe);
  const bool aF32 = aDyn && f32in;
  const int tid = threadIdx.x;
  const int tx = tid & 15, ty = tid >> 4;
  const int c0 = blockIdx.x * 128, r0 = blockIdx.y * 128;
  __shared__ float As[32*132];
  __shared__ float Bs[32*132];
  float acc[8][8] = {};
  const int ra = ty*4, rb = 64 + ty*4;
  const int ca = tx*4, cb = 64 + tx*4;
  for (int k0 = 0; k0 < K; k0 += 32) {
    #pragma unroll
    for (int l = 0; l < 16; ++l) {
      int idx = tid + l*256;          // 4096 elems each for A and B
      int kk = idx & 31, rr = idx >> 5;
      As[kk*132 + rr] = loadIn(A, (size_t)(r0+rr)*K + k0 + kk, aF32);
      Bs[kk*132 + rr] = loadIn(W, (size_t)(c0+rr)*K + k0 + kk, f32in);
    }
    __syncthreads();
    for (int kk = 0; kk < 32; ++kk) {
      const float* Ar = &As[kk*132];
      const float* Br = &Bs[kk*132];
      float4 a0 = *(const float4*)&Ar[ra];
      float4 a1 = *(const float4*)&Ar[rb];
      float4 b0 = *(const float4*)&Br[ca];
      float4 b1 = *(const float4*)&Br[cb];
      float a[8] = {a0.x,a0.y,a0.z,a0.w,a1.x,a1.y,a1.z,a1.w};
      float b[8] = {b0.x,b0.y,b0.z,b0.w,b1.x,b1.y,b1.z,b1.w};
      #pragma unroll
      for (int i=0;i<8;++i)
        #pragma unroll
        for (int j=0;j<8;++j) acc[i][j] += a[i]*b[j];
    }
    __syncthreads();
  }
  if (mode == 0) {
    #pragma unroll
    for (int i=0;i<8;++i){
      int r = r0 + (i<4 ? ra+i : rb+i-4);
      #pragma unroll
      for (int j=0;j<8;++j){
        int c = c0 + (j<4 ? ca+j : cb+j-4);
        if (f32in) ((float*)outAny)[(size_t)r*N + c] = acc[i][j];
        else       ((bf16*)outAny)[(size_t)r*N + c] = f2b(acc[i][j]);
      }
    }
  } else {
    int h0 = c0 >> 6;
    #pragma unroll
    for (int i=0;i<8;++i){
      int r = r0 + (i<4 ? ra+i : rb+i-4);
      int bb = r >> 11, s = r & 2047;
      float4 w0 = make_float4(acc[i][0],acc[i][1],acc[i][2],acc[i][3]);
      float4 w1 = make_float4(acc[i][4],acc[i][5],acc[i][6],acc[i][7]);
      *(float4*)&outf[(((size_t)bb*H + h0  )*SEQ + s)*DH + tx*4] = w0;
      *(float4*)&outf[(((size_t)bb*H + h0+1)*SEQ + s)*DH + tx*4] = w1;
    }
  }
}

// ---------------------------------------------------------------------------
// RoPE + dn scale, in place on fp32 head-major buffer (b,h,s,d). 1 wave = 1 row.
// ---------------------------------------------------------------------------
__global__ __launch_bounds__(256) void rope_kernel(float* __restrict__ x,
    const void* __restrict__ cosg, const void* __restrict__ sing,
    int H, float scale, const unsigned* __restrict__ probe)
{
  const bool f32in = probe_f32(probe);
  int row = blockIdx.x*4 + (threadIdx.x >> 6);
  int lane = threadIdx.x & 63;
  int s = row & 2047;
  int b = row / (H*SEQ);
  float* xr = x + (size_t)row*DH;
  float v  = xr[lane];
  float vp = __shfl_xor(v, 32, 64);
  size_t ci = ((size_t)b*SEQ + s)*DH + lane;
  float cv = loadIn(cosg, ci, f32in);
  float sv = loadIn(sing, ci, f32in);
  float rot = (lane < 32) ? -vp : vp;
  xr[lane] = (v*cv + rot*sv) * scale;
}

// transpose proj (M,D) -> projT (D,M) bf16
__global__ void tproj_kernel(const void* __restrict__ proj, bf16* __restrict__ projT,
                             const unsigned* __restrict__ probe){
  const bool f32in = probe_f32(probe);
  int idx = blockIdx.x*256 + threadIdx.x;   // 16384
  int d = idx >> 8, m = idx & 255;
  projT[idx] = f2b(loadIn(proj, (size_t)m*64 + d, f32in));
}

// ---------------------------------------------------------------------------
// phi_q: 16 rows per block; xp = xn @ proj^T, rowwise stab, exp, write bf16.
// ---------------------------------------------------------------------------
__global__ __launch_bounds__(256) void phi_q_kernel(const float* __restrict__ xn,
    const bf16* __restrict__ projT, bf16* __restrict__ phi)
{
  const int tid = threadIdx.x;
  __shared__ bf16 pt[16384];        // projT [d][m]
  __shared__ float xs[1024];        // 16 rows x 64
  __shared__ float dmat[16*256];
  __shared__ float pmax[256];
  __shared__ float sqv[16];
  __shared__ float smax[16];
  const size_t row0 = (size_t)blockIdx.x * 16;
  #pragma unroll
  for (int l=0;l<64;++l) pt[tid + l*256] = projT[tid + l*256];
  #pragma unroll
  for (int l=0;l<4;++l){ int idx = tid + l*256; xs[idx] = xn[row0*DH + idx]; }
  __syncthreads();
  if (tid < 16){
    float s = 0.f;
    #pragma unroll
    for (int d=0; d<64; ++d){ float v = xs[tid*64+d]; s += v*v; }
    sqv[tid] = 0.5f*s;
  }
  float pv[64];
  #pragma unroll
  for (int d=0; d<64; ++d) pv[d] = b2f(pt[d*256 + tid]);
  float dot[16];
  #pragma unroll
  for (int r=0;r<16;++r){
    const float4* xr = (const float4*)&xs[r*64];
    float acc = 0.f;
    #pragma unroll
    for (int d4=0; d4<16; ++d4){
      float4 xv = xr[d4];
      acc += xv.x*pv[4*d4] + xv.y*pv[4*d4+1] + xv.z*pv[4*d4+2] + xv.w*pv[4*d4+3];
    }
    dot[r] = acc;
    dmat[r*256 + tid] = acc;
  }
  __syncthreads();
  {
    int r = tid >> 4, sg = tid & 15;
    float mx = -1e30f;
    #pragma unroll
    for (int m2=0;m2<16;++m2) mx = fmaxf(mx, dmat[r*256 + sg*16 + m2]);
    pmax[tid] = mx;
  }
  __syncthreads();
  if (tid < 16){
    float mx = -1e30f;
    #pragma unroll
    for (int sg=0;sg<16;++sg) mx = fmaxf(mx, pmax[tid*16+sg]);
    smax[tid] = mx;
  }
  __syncthreads();
  #pragma unroll
  for (int r=0;r<16;++r){
    float val = (__expf(fminf(dot[r] - sqv[r] - smax[r], 0.f)) + EPSF) * 0.0625f;
    phi[(row0 + r)*MFEAT + tid] = f2b(val);
  }
}

// phi_k pass A: rowwise max of xp only -> rmaxk
__global__ __launch_bounds__(256) void phik_max_kernel(const float* __restrict__ xn,
    const bf16* __restrict__ projT, float* __restrict__ rmaxk)
{
  const int tid = threadIdx.x;
  __shared__ bf16 pt[16384];
  __shared__ float xs[1024];
  __shared__ float dmat[16*256];
  __shared__ float pmax[256];
  const size_t row0 = (size_t)blockIdx.x * 16;
  #pragma unroll
  for (int l=0;l<64;++l) pt[tid + l*256] = projT[tid + l*256];
  #pragma unroll
  for (int l=0;l<4;++l){ int idx = tid + l*256; xs[idx] = xn[row0*DH + idx]; }
  __syncthreads();
  float pv[64];
  #pragma unroll
  for (int d=0; d<64; ++d) pv[d] = b2f(pt[d*256 + tid]);
  #pragma unroll
  for (int r=0;r<16;++r){
    const float4* xr = (const float4*)&xs[r*64];
    float acc = 0.f;
    #pragma unroll
    for (int d4=0; d4<16; ++d4){
      float4 xv = xr[d4];
      acc += xv.x*pv[4*d4] + xv.y*pv[4*d4+1] + xv.z*pv[4*d4+2] + xv.w*pv[4*d4+3];
    }
    dmat[r*256 + tid] = acc;
  }
  __syncthreads();
  {
    int r = tid >> 4, sg = tid & 15;
    float mx = -1e30f;
    #pragma unroll
    for (int m2=0;m2<16;++m2) mx = fmaxf(mx, dmat[r*256 + sg*16 + m2]);
    pmax[tid] = mx;
  }
  __syncthreads();
  if (tid < 16){
    float mx = -1e30f;
    #pragma unroll
    for (int sg=0;sg<16;++sg) mx = fmaxf(mx, pmax[tid*16+sg]);
    rmaxk[row0 + tid] = mx;
  }
}

__global__ void stab_reduce_kernel(const float* __restrict__ rmaxk, float* __restrict__ stabk){
  __shared__ float red[256];
  int bk = blockIdx.x;
  float mx = -1e30f;
  for (int i = threadIdx.x; i < SEQ; i += 256) mx = fmaxf(mx, rmaxk[(size_t)bk*SEQ + i]);
  red[threadIdx.x] = mx; __syncthreads();
  for (int off=128; off>0; off>>=1){
    if ((int)threadIdx.x < off) red[threadIdx.x] = fmaxf(red[threadIdx.x], red[threadIdx.x+off]);
    __syncthreads();
  }
  if (threadIdx.x==0) stabk[bk] = red[0];
}

// phi_k pass C: recompute xp, apply global stab + local sq, exp -> bf16
__global__ __launch_bounds__(256) void phik_exp_kernel(const float* __restrict__ xn,
    const bf16* __restrict__ projT, const float* __restrict__ stabk,
    bf16* __restrict__ phi)
{
  const int tid = threadIdx.x;
  __shared__ bf16 pt[16384];
  __shared__ float xs[1024];
  __shared__ float sqv[16];
  const size_t row0 = (size_t)blockIdx.x * 16;
  const float stab = stabk[row0 >> 11];
  #pragma unroll
  for (int l=0;l<64;++l) pt[tid + l*256] = projT[tid + l*256];
  #pragma unroll
  for (int l=0;l<4;++l){ int idx = tid + l*256; xs[idx] = xn[row0*DH + idx]; }
  __syncthreads();
  if (tid < 16){
    float s = 0.f;
    #pragma unroll
    for (int d=0; d<64; ++d){ float v = xs[tid*64+d]; s += v*v; }
    sqv[tid] = 0.5f*s;
  }
  __syncthreads();
  float pv[64];
  #pragma unroll
  for (int d=0; d<64; ++d) pv[d] = b2f(pt[d*256 + tid]);
  #pragma unroll
  for (int r=0;r<16;++r){
    const float4* xr = (const float4*)&xs[r*64];
    float acc = 0.f;
    #pragma unroll
    for (int d4=0; d4<16; ++d4){
      float4 xv = xr[d4];
      acc += xv.x*pv[4*d4] + xv.y*pv[4*d4+1] + xv.z*pv[4*d4+2] + xv.w*pv[4*d4+3];
    }
    float val = (__expf(fminf(acc - sqv[r] - stab, 0.f)) + EPSF) * 0.0625f;
    phi[(row0 + r)*MFEAT + tid] = f2b(val);
  }
}

// ---------------------------------------------------------------------------
// kv/kz per-chunk sums: block = (bk, c); thread m accumulates phik[t,m]*v[t,:]
// ---------------------------------------------------------------------------
__global__ __launch_bounds__(256) void kvchunk_kernel(const bf16* __restrict__ phik,
    const float* __restrict__ vbuf, float* __restrict__ kv, float* __restrict__ kz)
{
  int blk = blockIdx.x; int bk = blk >> 4, c = blk & 15;
  const bf16* Kc = phik + ((size_t)bk*SEQ + c*128)*MFEAT;
  const float* Vc = vbuf + ((size_t)bk*SEQ + c*128)*DH;
  __shared__ float sV[128*64];
  for (int l=0;l<32;++l){ int idx = threadIdx.x + l*256; sV[idx] = Vc[idx]; }
  __syncthreads();
  int m = threadIdx.x;
  float acc[64] = {}; float az = 0.f;
  for (int t=0;t<128;++t){
    float ph = b2f(Kc[(size_t)t*MFEAT + m]);
    az += ph;
    const float4* vr = (const float4*)&sV[t*64];
    #pragma unroll
    for (int d4=0; d4<16; ++d4){
      float4 v4 = vr[d4];
      acc[d4*4+0] += ph*v4.x; acc[d4*4+1] += ph*v4.y;
      acc[d4*4+2] += ph*v4.z; acc[d4*4+3] += ph*v4.w;
    }
  }
  float* out = kv + (size_t)blk*MFEAT*DH + (size_t)m*DH;
  #pragma unroll
  for (int d4=0; d4<16; ++d4)
    ((float4*)out)[d4] = make_float4(acc[d4*4],acc[d4*4+1],acc[d4*4+2],acc[d4*4+3]);
  kz[(size_t)blk*MFEAT + m] = az;
}

// exclusive prefix over chunk axis
__global__ void scan_kernel(float* __restrict__ p, int inner, int nc, int total){
  int t = blockIdx.x*256 + threadIdx.x;
  if (t >= total) return;
  int outer = t / inner, rem = t - outer*inner;
  float* base = p + (size_t)outer*nc*inner + rem;
  float run = 0.f;
  for (int c=0;c<nc;++c){
    float v = base[(size_t)c*inner];
    base[(size_t)c*inner] = run;
    run += v;
  }
}

// ---------------------------------------------------------------------------
// Attention: block = (b, h, chunk). scores->mask->intra + inter + z terms.
// ---------------------------------------------------------------------------
__global__ __launch_bounds__(256) void attn_kernel(
    const bf16* __restrict__ phiq, const bf16* __restrict__ phik,
    const float* __restrict__ vbuf, const float* __restrict__ kvp,
    const float* __restrict__ kzp, bf16* __restrict__ attnout)
{
  const int tid = threadIdx.x;
  const int tx = tid & 15, ty = tid >> 4;
  int blk = blockIdx.x;
  int c = blk & 15, h = (blk >> 4) & 31, b = blk >> 9;
  int kvh = h >> 2;
  const bf16* Q  = phiq + ((size_t)(b*NHEAD+h)*SEQ + c*128)*MFEAT;
  const bf16* Kc = phik + ((size_t)(b*NKVH+kvh)*SEQ + c*128)*MFEAT;
  const float* Vc  = vbuf + ((size_t)(b*NKVH+kvh)*SEQ + c*128)*DH;
  const float* KVp = kvp + ((size_t)((b*NKVH+kvh)*NCH + c))*MFEAT*DH;
  const float* KZp = kzp + ((size_t)((b*NKVH+kvh)*NCH + c))*MFEAT;

  __shared__ float smem[12800];
  float* iz  = smem;
  float* ez  = smem + 128;
  float* ph1 = smem + 256;

  // ---- P1: scores = Q @ K^T (m tiles of 32), interleaved 8x8 ownership
  float accS[8][8] = {};
  {
    float* sA = ph1;            // [128][33]
    float* sB = ph1 + 4224;     // [128][33]
    for (int mt = 0; mt < MFEAT; mt += 32) {
      #pragma unroll
      for (int l = 0; l < 16; ++l) {
        int idx = tid + l*256;  // 4096
        int r = idx >> 5, m = idx & 31;
        sA[r*33+m] = b2f(Q [(size_t)r*MFEAT + mt + m]);
        sB[r*33+m] = b2f(Kc[(size_t)r*MFEAT + mt + m]);
      }
      __syncthreads();
      for (int km = 0; km < 32; ++km) {
        float a[8], bb[8];
        #pragma unroll
        for (int i=0;i<8;++i) a[i]  = sA[(ty+16*i)*33 + km];
        #pragma unroll
        for (int j=0;j<8;++j) bb[j] = sB[(tx+16*j)*33 + km];
        #pragma unroll
        for (int i=0;i<8;++i)
          #pragma unroll
          for (int j=0;j<8;++j) accS[i][j] += a[i]*bb[j];
      }
      __syncthreads();
    }
  }
  // ---- mask + write scores (bf16) + stage V (bf16)
  bf16* sS = (bf16*)ph1;                 // [128][130]
  bf16* sV = (bf16*)(ph1 + 8320);        // [128][66]
  #pragma unroll
  for (int i=0;i<8;++i)
    #pragma unroll
    for (int j=0;j<8;++j){
      int s = ty+16*i, t = tx+16*j;
      sS[s*130+t] = f2b(t<=s ? accS[i][j] : 0.f);
    }
  #pragma unroll
  for (int l=0;l<32;++l){
    int idx = tid + l*256;               // 8192
    int r = idx>>6, d = idx&63;
    sV[r*66+d] = f2b(Vc[idx]);
  }
  __syncthreads();
  if (tid < 128) {
    float z = 0.f;
    for (int t=0;t<128;++t) z += b2f(sS[tid*130+t]);
    iz[tid] = z;
  }
  __syncthreads();
  // ---- P2: intra = scores @ V
  float accC[8][4] = {};
  for (int t=0;t<128;++t){
    float bb[4];
    #pragma unroll
    for (int j=0;j<4;++j) bb[j] = b2f(sV[t*66 + tx+16*j]);
    #pragma unroll
    for (int i=0;i<8;++i){
      float a = b2f(sS[(ty+16*i)*130 + t]);
      #pragma unroll
      for (int j=0;j<4;++j) accC[i][j] += a*bb[j];
    }
  }
  __syncthreads();
  // ---- P3: inter = Q @ KVpre ; ez = Q @ KZpre
  float accI[8][4] = {};
  float zacc[8] = {};
  {
    float* sA2 = ph1;          // [128][33]
    float* sKV = ph1 + 4224;   // [32][65]
    float* sKZ = ph1 + 6304;   // [32]
    for (int mt=0; mt<MFEAT; mt+=32){
      #pragma unroll
      for (int l=0;l<16;++l){
        int idx = tid + l*256; int r = idx>>5, m = idx&31;
        sA2[r*33+m] = b2f(Q[(size_t)r*MFEAT + mt + m]);
      }
      #pragma unroll
      for (int l=0;l<8;++l){
        int idx = tid + l*256; int m = idx>>6, d = idx&63;   // 2048
        sKV[m*65+d] = KVp[(size_t)(mt+m)*DH + d];
      }
      if (tid < 32) sKZ[tid] = KZp[mt + tid];
      __syncthreads();
      for (int km=0;km<32;++km){
        float a[8];
        #pragma unroll
        for (int i=0;i<8;++i) a[i] = sA2[(ty+16*i)*33+km];
        float bb[4];
        #pragma unroll
        for (int j=0;j<4;++j) bb[j] = sKV[km*65 + tx+16*j];
        #pragma unroll
        for (int i=0;i<8;++i)
          #pragma unroll
          for (int j=0;j<4;++j) accI[i][j] += a[i]*bb[j];
        if (tx == 0){
          float kzv = sKZ[km];
          #pragma unroll
          for (int i=0;i<8;++i) zacc[i] += a[i]*kzv;
        }
      }
      __syncthreads();
    }
  }
  if (tx == 0){
    #pragma unroll
    for (int i=0;i<8;++i) ez[ty+16*i] = zacc[i];
  }
  __syncthreads();
  // ---- epilogue: out = (inter+intra)/(ez+iz+eps) -> attn[b,s,h,d] bf16
  #pragma unroll
  for (int i=0;i<8;++i){
    int s = ty+16*i;
    float inv = 1.0f / (ez[s] + iz[s] + EPSF);
    int sg = c*128 + s;
    size_t obase = (((size_t)b*SEQ + sg)*NHEAD + h)*DH;
    #pragma unroll
    for (int j=0;j<4;++j){
      int d = tx+16*j;
      attnout[obase + d] = f2b((accI[i][j] + accC[i][j]) * inv);
    }
  }
}

// ---------------------------------------------------------------------------
extern "C" void kernel_launch(void* const* d_in, const int* in_sizes, int n_in,
                              void* d_out, int out_size, void* d_ws, size_t ws_size,
                              hipStream_t stream)
{
  const void* hidden = d_in[0];
  const void* cosg   = d_in[1];
  const void* sing   = d_in[2];
  const void* Wq     = d_in[3];
  const void* Wk     = d_in[4];
  const void* Wv     = d_in[5];
  const void* Wo     = d_in[6];
  const void* proj   = d_in[7];
  const unsigned* probe = (const unsigned*)d_in[1];

  float* ws = (float*)d_ws;
  float* xnq   = ws;                    //  8388608 f  (q, then roped+scaled)
  float* xnk   = ws + 8388608;          //  2097152 f
  float* vbuf  = ws + 10485760;         //  2097152 f
  float* kv    = ws + 12582912;         //  4194304 f
  float* kz    = ws + 16777216;         //    65536 f
  float* rmaxk = ws + 16842752;         //    32768 f
  float* stabk = ws + 16875520;         //      256 f
  bf16* projT  = (bf16*)(ws + 16875776);  //  16384 bf16
  bf16* phiq   = (bf16*)(ws + 16883968);  //  33554432 bf16
  bf16* phik   = (bf16*)(ws + 33661184);  //  8388608 bf16
  bf16* attn   = (bf16*)(ws + 37855488);  //  8388608 bf16
  // total ws usage: ~42M floats = 168.2 MB

  const float dn = 0.3535533905932738f;  // 64^-0.25

  tproj_kernel<<<64, 256, 0, stream>>>(proj, projT, probe);

  // projections (head-major fp32 out)
  gemm_bt<<<dim3(16,32), 256, 0, stream>>>(hidden, Wq, xnq, nullptr, 2048, 2048, NHEAD, 1, 1, probe);
  gemm_bt<<<dim3(4,32),  256, 0, stream>>>(hidden, Wk, xnk, nullptr, 2048,  512, NKVH, 1, 1, probe);
  gemm_bt<<<dim3(4,32),  256, 0, stream>>>(hidden, Wv, vbuf, nullptr, 2048,  512, NKVH, 1, 1, probe);

  // RoPE + dn scaling (in-place)
  rope_kernel<<<32768, 256, 0, stream>>>(xnq, cosg, sing, NHEAD, dn, probe);
  rope_kernel<<<8192,  256, 0, stream>>>(xnk, cosg, sing, NKVH, dn, probe);

  // features
  phi_q_kernel<<<8192, 256, 0, stream>>>(xnq, projT, phiq);
  phik_max_kernel<<<2048, 256, 0, stream>>>(xnk, projT, rmaxk);
  stab_reduce_kernel<<<16, 256, 0, stream>>>(rmaxk, stabk);
  phik_exp_kernel<<<2048, 256, 0, stream>>>(xnk, projT, stabk, phik);

  // chunk kv/kz states + exclusive prefix
  kvchunk_kernel<<<256, 256, 0, stream>>>(phik, vbuf, kv, kz);
  scan_kernel<<<1024, 256, 0, stream>>>(kv, MFEAT*DH, NCH, 16*MFEAT*DH);
  scan_kernel<<<16,   256, 0, stream>>>(kz, MFEAT,    NCH, 16*MFEAT);

  // attention
  attn_kernel<<<1024, 256, 0, stream>>>(phiq, phik, vbuf, kv, kz, attn);

  // output projection (dtype of output follows input dtype)
  gemm_bt<<<dim3(16,32), 256, 0, stream>>>(attn, Wo, nullptr, d_out, 2048, 2048, 0, 0, 0, probe);
}

// Round 3
// 621.166 us; speedup vs baseline: 9.1551x; 9.1551x over previous
//
#include <hip/hip_runtime.h>
#include <hip/hip_bf16.h>

// Problem constants (B=2, S=2048, HID=2048, NH=32, NKV=8, D=64, M=256, CHUNK=128)
#define SEQ   2048
#define NHEAD 32
#define NKVH  8
#define DH    64
#define MFEAT 256
#define NCH   16
#define EPSF  1e-6f

typedef __hip_bfloat16 bf16;
typedef unsigned short u16;
typedef __attribute__((ext_vector_type(8))) short short8;   // 8 bf16 (4 VGPRs)
typedef __attribute__((ext_vector_type(4))) float f32x4;    // 4 fp32 acc

__device__ __forceinline__ float b2f(bf16 x){ return __bfloat162float(x); }
__device__ __forceinline__ bf16  f2b(float x){ return __float2bfloat16(x); }
__device__ __forceinline__ u16   f2u(float x){ bf16 h = __float2bfloat16(x); return *reinterpret_cast<u16*>(&h); }

// dtype probe: d_in[1] is cos; cos[0]==1.0 exactly.
// fp32 -> word0 = 0x3F800000 (low16==0). bf16-packed -> low16!=0.
__device__ __forceinline__ bool probe_f32(const unsigned* __restrict__ p){
  return (p[0] & 0xFFFFu) == 0u;
}
__device__ __forceinline__ float loadIn(const void* __restrict__ ptr, size_t idx, bool f32){
  return f32 ? ((const float*)ptr)[idx] : b2f(((const bf16*)ptr)[idx]);
}

// async 16B global -> LDS (wave-uniform LDS base + lane*16)
__device__ __forceinline__ void cp16(u16* lds, const u16* g){
  __builtin_amdgcn_global_load_lds((const __attribute__((address_space(1))) unsigned*)g,
      (__attribute__((address_space(3))) unsigned*)lds, 16, 0, 0);
}

#define MFMA16(a,b,c) __builtin_amdgcn_mfma_f32_16x16x32_bf16(a,b,c,0,0,0)

// ---------------------------------------------------------------------------
// dtype convert: src (fp32 or bf16 per probe) -> bf16 (u16) dst
// ---------------------------------------------------------------------------
__global__ __launch_bounds__(256) void conv_kernel(const void* __restrict__ src,
    u16* __restrict__ dst, const unsigned* __restrict__ probe)
{
  const bool f32in = probe_f32(probe);
  size_t i = ((size_t)blockIdx.x*256 + threadIdx.x)*4;
  #pragma unroll
  for (int j=0;j<4;++j) dst[i+j] = f2u(loadIn(src, i+j, f32in));
}

// ---------------------------------------------------------------------------
// MFMA GEMM: C[r,c] = sum_k A[r,k]*W[c,k]; A,W row-major bf16 (u16).
// 128x128 tile, BK=32, 4 waves (2x2 of 64x64), m97 structure.
// mode 0: outAny[r*N+c] (dtype probed f32/bf16)
// mode 1: qkv scatter -> oq/ok/ov fp32 head-major [b,h,s,d]
// ---------------------------------------------------------------------------
__global__ __launch_bounds__(256) void gemm_mfma(const u16* __restrict__ A,
    const u16* __restrict__ W, float* __restrict__ oq, float* __restrict__ ok,
    float* __restrict__ ov, void* __restrict__ outAny, int K, int N, int mode,
    const unsigned* __restrict__ probe)
{
  __shared__ __align__(16) u16 sA[4096];
  __shared__ __align__(16) u16 sB[4096];
  const int tid = threadIdx.x;
  const int lane = tid & 63, wave = tid >> 6;
  const int c0 = blockIdx.x*128, r0 = blockIdx.y*128;
  const int wm = wave & 1, wn = wave >> 1;
  f32x4 acc[4][4] = {};

  const int ch0 = wave*64 + lane, ch1 = 256 + wave*64 + lane;
  const u16* gA0 = A + (size_t)(r0 + (ch0>>2))*K + (ch0&3)*8;
  const u16* gA1 = A + (size_t)(r0 + (ch1>>2))*K + (ch1&3)*8;
  const u16* gB0 = W + (size_t)(c0 + (ch0>>2))*K + (ch0&3)*8;
  const u16* gB1 = W + (size_t)(c0 + (ch1>>2))*K + (ch1&3)*8;
  u16* lA0 = &sA[(wave*64)*8];  u16* lA1 = &sA[(256 + wave*64)*8];
  u16* lB0 = &sB[(wave*64)*8];  u16* lB1 = &sB[(256 + wave*64)*8];

  const u16* pA = &sA[(wm*64 + (lane&15))*32 + (lane>>4)*8];
  const u16* pB = &sB[(wn*64 + (lane&15))*32 + (lane>>4)*8];

  for (int k0 = 0; k0 < K; k0 += 32) {
    cp16(lA0, gA0 + k0); cp16(lA1, gA1 + k0);
    cp16(lB0, gB0 + k0); cp16(lB1, gB1 + k0);
    __syncthreads();
    short8 af[4], bfv[4];
    #pragma unroll
    for (int mt=0;mt<4;++mt) af[mt]  = *(const short8*)(pA + mt*512);
    #pragma unroll
    for (int nt=0;nt<4;++nt) bfv[nt] = *(const short8*)(pB + nt*512);
    #pragma unroll
    for (int mt=0;mt<4;++mt)
      #pragma unroll
      for (int nt=0;nt<4;++nt)
        acc[mt][nt] = MFMA16(af[mt], bfv[nt], acc[mt][nt]);
    __syncthreads();
  }

  const int rbase = r0 + wm*64 + (lane>>4)*4;   // + mt*16 + rg
  const int cbase = c0 + wn*64 + (lane&15);     // + nt*16
  if (mode == 0) {
    const bool f32o = probe_f32(probe);
    #pragma unroll
    for (int mt=0;mt<4;++mt)
      #pragma unroll
      for (int nt=0;nt<4;++nt)
        #pragma unroll
        for (int rg=0;rg<4;++rg){
          int r = rbase + mt*16 + rg, c = cbase + nt*16;
          float v = acc[mt][nt][rg];
          if (f32o) ((float*)outAny)[(size_t)r*N + c] = v;
          else      ((u16*)outAny)[(size_t)r*N + c] = f2u(v);
        }
  } else {
    #pragma unroll
    for (int nt=0;nt<4;++nt){
      int cc = cbase + nt*16;
      float* dst; int H2, cl;
      if (cc < 2048){ dst = oq; H2 = 32; cl = cc; }
      else if (cc < 2560){ dst = ok; H2 = 8; cl = cc - 2048; }
      else { dst = ov; H2 = 8; cl = cc - 2560; }
      int hh = cl>>6, dd = cl&63;
      #pragma unroll
      for (int mt=0;mt<4;++mt)
        #pragma unroll
        for (int rg=0;rg<4;++rg){
          int r = rbase + mt*16 + rg;
          dst[(((size_t)(r>>11)*H2 + hh)*SEQ + (r&2047))*DH + dd] = acc[mt][nt][rg];
        }
    }
  }
}

// ---------------------------------------------------------------------------
// RoPE + dn scale, in place on fp32 head-major buffer (b,h,s,d). 1 wave = 1 row.
// ---------------------------------------------------------------------------
__global__ __launch_bounds__(256) void rope_kernel(float* __restrict__ x,
    const void* __restrict__ cosg, const void* __restrict__ sing,
    int H, float scale, const unsigned* __restrict__ probe)
{
  const bool f32in = probe_f32(probe);
  int row = blockIdx.x*4 + (threadIdx.x >> 6);
  int lane = threadIdx.x & 63;
  int s = row & 2047;
  int b = row / (H*SEQ);
  float* xr = x + (size_t)row*DH;
  float v  = xr[lane];
  float vp = __shfl_xor(v, 32, 64);
  size_t ci = ((size_t)b*SEQ + s)*DH + lane;
  float cv = loadIn(cosg, ci, f32in);
  float sv = loadIn(sing, ci, f32in);
  float rot = (lane < 32) ? -vp : vp;
  xr[lane] = (v*cv + rot*sv) * scale;
}

// transpose proj (M,D) -> projT (D,M) bf16
__global__ void tproj_kernel(const void* __restrict__ proj, bf16* __restrict__ projT,
                             const unsigned* __restrict__ probe){
  const bool f32in = probe_f32(probe);
  int idx = blockIdx.x*256 + threadIdx.x;   // 16384
  int d = idx >> 8, m = idx & 255;
  projT[idx] = f2b(loadIn(proj, (size_t)m*64 + d, f32in));
}

// ---------------------------------------------------------------------------
// phi_q: 16 rows per block; xp = xn @ proj^T, rowwise stab, exp, write bf16.
// ---------------------------------------------------------------------------
__global__ __launch_bounds__(256) void phi_q_kernel(const float* __restrict__ xn,
    const bf16* __restrict__ projT, bf16* __restrict__ phi)
{
  const int tid = threadIdx.x;
  __shared__ bf16 pt[16384];
  __shared__ float xs[1024];
  __shared__ float dmat[16*256];
  __shared__ float pmax[256];
  __shared__ float sqv[16];
  __shared__ float smax[16];
  const size_t row0 = (size_t)blockIdx.x * 16;
  #pragma unroll
  for (int l=0;l<64;++l) pt[tid + l*256] = projT[tid + l*256];
  #pragma unroll
  for (int l=0;l<4;++l){ int idx = tid + l*256; xs[idx] = xn[row0*DH + idx]; }
  __syncthreads();
  if (tid < 16){
    float s = 0.f;
    #pragma unroll
    for (int d=0; d<64; ++d){ float v = xs[tid*64+d]; s += v*v; }
    sqv[tid] = 0.5f*s;
  }
  float pv[64];
  #pragma unroll
  for (int d=0; d<64; ++d) pv[d] = b2f(pt[d*256 + tid]);
  float dot[16];
  #pragma unroll
  for (int r=0;r<16;++r){
    const float4* xr = (const float4*)&xs[r*64];
    float acc = 0.f;
    #pragma unroll
    for (int d4=0; d4<16; ++d4){
      float4 xv = xr[d4];
      acc += xv.x*pv[4*d4] + xv.y*pv[4*d4+1] + xv.z*pv[4*d4+2] + xv.w*pv[4*d4+3];
    }
    dot[r] = acc;
    dmat[r*256 + tid] = acc;
  }
  __syncthreads();
  {
    int r = tid >> 4, sg = tid & 15;
    float mx = -1e30f;
    #pragma unroll
    for (int m2=0;m2<16;++m2) mx = fmaxf(mx, dmat[r*256 + sg*16 + m2]);
    pmax[tid] = mx;
  }
  __syncthreads();
  if (tid < 16){
    float mx = -1e30f;
    #pragma unroll
    for (int sg=0;sg<16;++sg) mx = fmaxf(mx, pmax[tid*16+sg]);
    smax[tid] = mx;
  }
  __syncthreads();
  #pragma unroll
  for (int r=0;r<16;++r){
    float val = (__expf(fminf(dot[r] - sqv[r] - smax[r], 0.f)) + EPSF) * 0.0625f;
    phi[(row0 + r)*MFEAT + tid] = f2b(val);
  }
}

// phi_k pass A: rowwise max of xp only -> rmaxk
__global__ __launch_bounds__(256) void phik_max_kernel(const float* __restrict__ xn,
    const bf16* __restrict__ projT, float* __restrict__ rmaxk)
{
  const int tid = threadIdx.x;
  __shared__ bf16 pt[16384];
  __shared__ float xs[1024];
  __shared__ float dmat[16*256];
  __shared__ float pmax[256];
  const size_t row0 = (size_t)blockIdx.x * 16;
  #pragma unroll
  for (int l=0;l<64;++l) pt[tid + l*256] = projT[tid + l*256];
  #pragma unroll
  for (int l=0;l<4;++l){ int idx = tid + l*256; xs[idx] = xn[row0*DH + idx]; }
  __syncthreads();
  float pv[64];
  #pragma unroll
  for (int d=0; d<64; ++d) pv[d] = b2f(pt[d*256 + tid]);
  #pragma unroll
  for (int r=0;r<16;++r){
    const float4* xr = (const float4*)&xs[r*64];
    float acc = 0.f;
    #pragma unroll
    for (int d4=0; d4<16; ++d4){
      float4 xv = xr[d4];
      acc += xv.x*pv[4*d4] + xv.y*pv[4*d4+1] + xv.z*pv[4*d4+2] + xv.w*pv[4*d4+3];
    }
    dmat[r*256 + tid] = acc;
  }
  __syncthreads();
  {
    int r = tid >> 4, sg = tid & 15;
    float mx = -1e30f;
    #pragma unroll
    for (int m2=0;m2<16;++m2) mx = fmaxf(mx, dmat[r*256 + sg*16 + m2]);
    pmax[tid] = mx;
  }
  __syncthreads();
  if (tid < 16){
    float mx = -1e30f;
    #pragma unroll
    for (int sg=0;sg<16;++sg) mx = fmaxf(mx, pmax[tid*16+sg]);
    rmaxk[row0 + tid] = mx;
  }
}

__global__ void stab_reduce_kernel(const float* __restrict__ rmaxk, float* __restrict__ stabk){
  __shared__ float red[256];
  int bk = blockIdx.x;
  float mx = -1e30f;
  for (int i = threadIdx.x; i < SEQ; i += 256) mx = fmaxf(mx, rmaxk[(size_t)bk*SEQ + i]);
  red[threadIdx.x] = mx; __syncthreads();
  for (int off=128; off>0; off>>=1){
    if ((int)threadIdx.x < off) red[threadIdx.x] = fmaxf(red[threadIdx.x], red[threadIdx.x+off]);
    __syncthreads();
  }
  if (threadIdx.x==0) stabk[bk] = red[0];
}

// phi_k pass C: recompute xp, apply global stab + local sq, exp -> bf16
__global__ __launch_bounds__(256) void phik_exp_kernel(const float* __restrict__ xn,
    const bf16* __restrict__ projT, const float* __restrict__ stabk,
    bf16* __restrict__ phi)
{
  const int tid = threadIdx.x;
  __shared__ bf16 pt[16384];
  __shared__ float xs[1024];
  __shared__ float sqv[16];
  const size_t row0 = (size_t)blockIdx.x * 16;
  const float stab = stabk[row0 >> 11];
  #pragma unroll
  for (int l=0;l<64;++l) pt[tid + l*256] = projT[tid + l*256];
  #pragma unroll
  for (int l=0;l<4;++l){ int idx = tid + l*256; xs[idx] = xn[row0*DH + idx]; }
  __syncthreads();
  if (tid < 16){
    float s = 0.f;
    #pragma unroll
    for (int d=0; d<64; ++d){ float v = xs[tid*64+d]; s += v*v; }
    sqv[tid] = 0.5f*s;
  }
  __syncthreads();
  float pv[64];
  #pragma unroll
  for (int d=0; d<64; ++d) pv[d] = b2f(pt[d*256 + tid]);
  #pragma unroll
  for (int r=0;r<16;++r){
    const float4* xr = (const float4*)&xs[r*64];
    float acc = 0.f;
    #pragma unroll
    for (int d4=0; d4<16; ++d4){
      float4 xv = xr[d4];
      acc += xv.x*pv[4*d4] + xv.y*pv[4*d4+1] + xv.z*pv[4*d4+2] + xv.w*pv[4*d4+3];
    }
    float val = (__expf(fminf(acc - sqv[r] - stab, 0.f)) + EPSF) * 0.0625f;
    phi[(row0 + r)*MFEAT + tid] = f2b(val);
  }
}

// ---------------------------------------------------------------------------
// kv/kz per-chunk sums: block = (bk, c); thread m accumulates phik[t,m]*v[t,:]
// ---------------------------------------------------------------------------
__global__ __launch_bounds__(256) void kvchunk_kernel(const bf16* __restrict__ phik,
    const float* __restrict__ vbuf, float* __restrict__ kv, float* __restrict__ kz)
{
  int blk = blockIdx.x; int bk = blk >> 4, c = blk & 15;
  const bf16* Kc = phik + ((size_t)bk*SEQ + c*128)*MFEAT;
  const float* Vc = vbuf + ((size_t)bk*SEQ + c*128)*DH;
  __shared__ float sV[128*64];
  for (int l=0;l<32;++l){ int idx = threadIdx.x + l*256; sV[idx] = Vc[idx]; }
  __syncthreads();
  int m = threadIdx.x;
  float acc[64] = {}; float az = 0.f;
  for (int t=0;t<128;++t){
    float ph = b2f(Kc[(size_t)t*MFEAT + m]);
    az += ph;
    const float4* vr = (const float4*)&sV[t*64];
    #pragma unroll
    for (int d4=0; d4<16; ++d4){
      float4 v4 = vr[d4];
      acc[d4*4+0] += ph*v4.x; acc[d4*4+1] += ph*v4.y;
      acc[d4*4+2] += ph*v4.z; acc[d4*4+3] += ph*v4.w;
    }
  }
  float* out = kv + (size_t)blk*MFEAT*DH + (size_t)m*DH;
  #pragma unroll
  for (int d4=0; d4<16; ++d4)
    ((float4*)out)[d4] = make_float4(acc[d4*4],acc[d4*4+1],acc[d4*4+2],acc[d4*4+3]);
  kz[(size_t)blk*MFEAT + m] = az;
}

// exclusive prefix over chunk axis
__global__ void scan_kernel(float* __restrict__ p, int inner, int nc, int total){
  int t = blockIdx.x*256 + threadIdx.x;
  if (t >= total) return;
  int outer = t / inner, rem = t - outer*inner;
  float* base = p + (size_t)outer*nc*inner + rem;
  float run = 0.f;
  for (int c=0;c<nc;++c){
    float v = base[(size_t)c*inner];
    base[(size_t)c*inner] = run;
    run += v;
  }
}

// ---------------------------------------------------------------------------
// MFMA attention: block = (b,h,chunk). 4 waves, each owns 32 rows.
// P1/P3 fused over feat chunks of 32: S += Q*K^T, O += Q*[KVpre|KZpre]
// mask S in regs -> P to LDS (bf16, stride 136); V^T staged with ones row 64.
// P2: O += P*[V|1]^T.  z (col 64) = ez+iz -> divide -> store (b,s,h,d) bf16.
// ---------------------------------------------------------------------------
__global__ __launch_bounds__(256) void attn_mfma(
    const u16* __restrict__ phiq, const u16* __restrict__ phik,
    const float* __restrict__ vbuf, const float* __restrict__ kvp,
    const float* __restrict__ kzp, u16* __restrict__ attnout)
{
  __shared__ __align__(16) u16 smem[28288];
  __shared__ float sZ[128];
  const int tid = threadIdx.x, lane = tid & 63, wave = tid >> 6;
  const int blk = blockIdx.x;
  const int c = blk & 15, h = (blk >> 4) & 31, b = blk >> 9;
  const int kvh = h >> 2;
  const u16* Q   = phiq + (((size_t)(b*NHEAD+h)*SEQ) + c*128)*MFEAT;
  const u16* Kc  = phik + (((size_t)(b*NKVH+kvh)*SEQ) + c*128)*MFEAT;
  const float* Vc  = vbuf + (((size_t)(b*NKVH+kvh)*SEQ) + c*128)*DH;
  const float* KVp = kvp + ((size_t)((b*NKVH+kvh)*NCH + c))*MFEAT*DH;
  const float* KZp = kzp + ((size_t)((b*NKVH+kvh)*NCH + c))*MFEAT;

  u16* sQ   = smem;            // [128][32]
  u16* sK   = smem + 4096;     // [128][32]
  u16* sKVT = smem + 8192;     // [80][72]  row 64 = KZpre, 65..79 unused
  u16* sP   = smem;            // [128][136]
  u16* sVT  = smem + 17408;    // [80][136] row 64 = ones, 65..79 unused

  f32x4 accS[2][8] = {};
  f32x4 accO[2][5] = {};

  const int ch0 = wave*64 + lane, ch1 = 256 + wave*64 + lane;
  const u16* gQ0 = Q  + (ch0>>2)*MFEAT + (ch0&3)*8;
  const u16* gQ1 = Q  + (ch1>>2)*MFEAT + (ch1&3)*8;
  const u16* gK0 = Kc + (ch0>>2)*MFEAT + (ch0&3)*8;
  const u16* gK1 = Kc + (ch1>>2)*MFEAT + (ch1&3)*8;
  u16* lQ0 = &sQ[(wave*64)*8];  u16* lQ1 = &sQ[(256+wave*64)*8];
  u16* lK0 = &sK[(wave*64)*8];  u16* lK1 = &sK[(256+wave*64)*8];

  for (int k0 = 0; k0 < MFEAT; k0 += 32) {
    cp16(lQ0, gQ0 + k0); cp16(lQ1, gQ1 + k0);
    cp16(lK0, gK0 + k0); cp16(lK1, gK1 + k0);
    // stage KVpre^T chunk (32 m x 64 d) + KZ row, bf16
    #pragma unroll
    for (int i=0;i<8;++i){
      int idx = tid + i*256;   // 2048
      int m = idx >> 6, d = idx & 63;
      sKVT[d*72 + m] = f2u(KVp[(size_t)(k0+m)*DH + d]);
    }
    if (tid < 32) sKVT[64*72 + tid] = f2u(KZp[k0 + tid]);
    __syncthreads();
    short8 af0, af1;
    const u16* pQ = &sQ[(wave*32 + (lane&15))*32 + (lane>>4)*8];
    af0 = *(const short8*)(pQ);
    af1 = *(const short8*)(pQ + 512);
    #pragma unroll
    for (int nt=0;nt<8;++nt){
      short8 bk = *(const short8*)&sK[(nt*16 + (lane&15))*32 + (lane>>4)*8];
      accS[0][nt] = MFMA16(af0, bk, accS[0][nt]);
      accS[1][nt] = MFMA16(af1, bk, accS[1][nt]);
    }
    #pragma unroll
    for (int nt=0;nt<5;++nt){
      short8 bi = *(const short8*)&sKVT[(nt*16 + (lane&15))*72 + (lane>>4)*8];
      accO[0][nt] = MFMA16(af0, bi, accO[0][nt]);
      accO[1][nt] = MFMA16(af1, bi, accO[1][nt]);
    }
    __syncthreads();
  }

  // mask + write P (bf16, stride 136); build V^T with ones row
  #pragma unroll
  for (int mt=0;mt<2;++mt){
    int rowb = wave*32 + mt*16 + (lane>>4)*4;
    #pragma unroll
    for (int nt=0;nt<8;++nt){
      int col = nt*16 + (lane&15);
      #pragma unroll
      for (int rg=0;rg<4;++rg){
        int row = rowb + rg;
        float v = (col <= row) ? accS[mt][nt][rg] : 0.f;
        sP[row*136 + col] = f2u(v);
      }
    }
  }
  #pragma unroll
  for (int i=0;i<32;++i){
    int idx = tid + i*256;   // 8192
    int t = idx >> 6, d = idx & 63;
    sVT[d*136 + t] = f2u(Vc[idx]);
  }
  if (tid < 128) sVT[64*136 + tid] = 0x3F80;  // bf16 1.0
  __syncthreads();

  // P2: O += P @ [V|1]
  #pragma unroll
  for (int kc=0;kc<4;++kc){
    const u16* pP = &sP[(wave*32 + (lane&15))*136 + kc*32 + (lane>>4)*8];
    short8 pa0 = *(const short8*)(pP);
    short8 pa1 = *(const short8*)(pP + 16*136);
    #pragma unroll
    for (int nt=0;nt<5;++nt){
      short8 bv = *(const short8*)&sVT[(nt*16 + (lane&15))*136 + kc*32 + (lane>>4)*8];
      accO[0][nt] = MFMA16(pa0, bv, accO[0][nt]);
      accO[1][nt] = MFMA16(pa1, bv, accO[1][nt]);
    }
  }

  // z broadcast + divide + store
  if ((lane & 15) == 0){
    #pragma unroll
    for (int mt=0;mt<2;++mt){
      int rowb = wave*32 + mt*16 + (lane>>4)*4;
      #pragma unroll
      for (int rg=0;rg<4;++rg) sZ[rowb + rg] = accO[mt][4][rg];
    }
  }
  __syncthreads();
  const int d0 = lane & 15;
  #pragma unroll
  for (int mt=0;mt<2;++mt){
    int rowb = wave*32 + mt*16 + (lane>>4)*4;
    #pragma unroll
    for (int rg=0;rg<4;++rg){
      int row = rowb + rg;
      float inv = 1.0f / (sZ[row] + EPSF);
      int sg = c*128 + row;
      size_t ob = (((size_t)b*SEQ + sg)*NHEAD + h)*DH;
      #pragma unroll
      for (int nt=0;nt<4;++nt)
        attnout[ob + nt*16 + d0] = f2u(accO[mt][nt][rg] * inv);
    }
  }
}

// ---------------------------------------------------------------------------
extern "C" void kernel_launch(void* const* d_in, const int* in_sizes, int n_in,
                              void* d_out, int out_size, void* d_ws, size_t ws_size,
                              hipStream_t stream)
{
  const void* hidden = d_in[0];
  const void* cosg   = d_in[1];
  const void* sing   = d_in[2];
  const void* Wq     = d_in[3];
  const void* Wk     = d_in[4];
  const void* Wv     = d_in[5];
  const void* Wo     = d_in[6];
  const void* proj   = d_in[7];
  const unsigned* probe = (const unsigned*)d_in[1];

  float* ws = (float*)d_ws;
  // overlays (stream-order safe):
  //   [0, 8388608): xnq (until phi_q) -> then kv/kz/rmaxk/stabk
  float* xnq   = ws;                       // 8388608 f
  float* kv    = ws;                       // 4194304 f (after phi_q)
  float* kz    = ws + 4194304;             //   65536 f
  float* rmaxk = ws + 4259840;             //   32768 f
  float* stabk = ws + 4292608;             //     256 f
  float* xnk   = ws + 8388608;             // 2097152 f
  float* vbuf  = ws + 10485760;            // 2097152 f
  bf16*  projT = (bf16*)(ws + 12582912);   //   16384 bf16 (8192 f)
  bf16*  phiq  = (bf16*)(ws + 12591104);   // 33554432 bf16 (16777216 f)
  bf16*  phik  = (bf16*)(ws + 29368320);   //  8388608 bf16 (4194304 f)
  u16*   hb    = (u16*) (ws + 33562624);   //  8388608 bf16 (hidden; attn later)
  u16*   attn  = (u16*) (ws + 33562624);   //  (same region, after QKV gemm)
  u16*   wqkv  = (u16*) (ws + 37756928);   //  6291456 bf16 (3145728 f)
  u16*   wob   = (u16*) (ws + 37756928);   //  (same region, after QKV gemm)
  // total: 40902656 f = 163.6 MB

  const float dn = 0.3535533905932738f;  // 64^-0.25

  // converts: hidden + Wq|Wk|Wv (concatenated 3072x2048)
  conv_kernel<<<8192, 256, 0, stream>>>(hidden, hb, probe);
  conv_kernel<<<4096, 256, 0, stream>>>(Wq, wqkv,           probe);
  conv_kernel<<<1024, 256, 0, stream>>>(Wk, wqkv + 4194304, probe);
  conv_kernel<<<1024, 256, 0, stream>>>(Wv, wqkv + 5242880, probe);
  tproj_kernel<<<64, 256, 0, stream>>>(proj, projT, probe);

  // fused QKV projection (fp32 head-major out)
  gemm_mfma<<<dim3(24,32), 256, 0, stream>>>(hb, wqkv, xnq, xnk, vbuf, nullptr,
                                             2048, 3072, 1, probe);
  // Wo convert (reuses wqkv region; ordered after QKV gemm)
  conv_kernel<<<4096, 256, 0, stream>>>(Wo, wob, probe);

  // RoPE + dn scaling (in-place)
  rope_kernel<<<32768, 256, 0, stream>>>(xnq, cosg, sing, NHEAD, dn, probe);
  rope_kernel<<<8192,  256, 0, stream>>>(xnk, cosg, sing, NKVH, dn, probe);

  // features
  phi_q_kernel<<<8192, 256, 0, stream>>>(xnq, projT, phiq);
  phik_max_kernel<<<2048, 256, 0, stream>>>(xnk, projT, rmaxk);
  stab_reduce_kernel<<<16, 256, 0, stream>>>(rmaxk, stabk);
  phik_exp_kernel<<<2048, 256, 0, stream>>>(xnk, projT, stabk, phik);

  // chunk kv/kz states + exclusive prefix (kv overlays dead xnq region)
  kvchunk_kernel<<<256, 256, 0, stream>>>(phik, vbuf, kv, kz);
  scan_kernel<<<1024, 256, 0, stream>>>(kv, MFEAT*DH, NCH, 16*MFEAT*DH);
  scan_kernel<<<16,   256, 0, stream>>>(kz, MFEAT,    NCH, 16*MFEAT);

  // MFMA attention
  attn_mfma<<<1024, 256, 0, stream>>>((const u16*)phiq, (const u16*)phik,
                                      vbuf, kv, kz, attn);

  // output projection (out dtype follows input dtype)
  gemm_mfma<<<dim3(16,32), 256, 0, stream>>>(attn, wob, nullptr, nullptr, nullptr,
                                             d_out, 2048, 2048, 0, probe);
}

// Round 4
// 498.980 us; speedup vs baseline: 11.3969x; 1.2449x over previous
//
#include <hip/hip_runtime.h>
#include <hip/hip_bf16.h>

// Problem constants (B=2, S=2048, HID=2048, NH=32, NKV=8, D=64, M=256, CHUNK=128)
#define SEQ   2048
#define NHEAD 32
#define NKVH  8
#define DH    64
#define MFEAT 256
#define NCH   16
#define EPSF  1e-6f

typedef __hip_bfloat16 bf16;
typedef unsigned short u16;
typedef __attribute__((ext_vector_type(8))) short short8;   // 8 bf16 (4 VGPRs)
typedef __attribute__((ext_vector_type(4))) float f32x4;    // 4 fp32 acc

__device__ __forceinline__ float b2f(bf16 x){ return __bfloat162float(x); }
__device__ __forceinline__ bf16  f2b(float x){ return __float2bfloat16(x); }
__device__ __forceinline__ u16   f2u(float x){ bf16 h = __float2bfloat16(x); return *reinterpret_cast<u16*>(&h); }

// dtype probe: d_in[1] is cos; cos[0]==1.0 exactly.
// fp32 -> word0 = 0x3F800000 (low16==0). bf16-packed -> low16!=0.
__device__ __forceinline__ bool probe_f32(const unsigned* __restrict__ p){
  return (p[0] & 0xFFFFu) == 0u;
}
__device__ __forceinline__ float loadIn(const void* __restrict__ ptr, size_t idx, bool f32){
  return f32 ? ((const float*)ptr)[idx] : b2f(((const bf16*)ptr)[idx]);
}

// async 16B global -> LDS (wave-uniform LDS base + lane*16)
__device__ __forceinline__ void cp16(u16* lds, const u16* g){
  __builtin_amdgcn_global_load_lds((const __attribute__((address_space(1))) unsigned*)g,
      (__attribute__((address_space(3))) unsigned*)lds, 16, 0, 0);
}

#define MFMA16(a,b,c) __builtin_amdgcn_mfma_f32_16x16x32_bf16(a,b,c,0,0,0)

// ---------------------------------------------------------------------------
// dtype convert: src (fp32 or bf16 per probe) -> bf16 (u16) dst
// ---------------------------------------------------------------------------
__global__ __launch_bounds__(256) void conv_kernel(const void* __restrict__ src,
    u16* __restrict__ dst, const unsigned* __restrict__ probe)
{
  const bool f32in = probe_f32(probe);
  size_t i = ((size_t)blockIdx.x*256 + threadIdx.x)*4;
  #pragma unroll
  for (int j=0;j<4;++j) dst[i+j] = f2u(loadIn(src, i+j, f32in));
}

// ---------------------------------------------------------------------------
// MFMA GEMM: C[r,c] = sum_k A[r,k]*W[c,k]; A,W row-major bf16 (u16).
// 128x128 tile, BK=32, 4 waves (2x2 of 64x64), m97 structure.
// mode 0: outAny[r*N+c] (dtype probed f32/bf16)
// mode 1: qkv scatter -> oq/ok/ov fp32 head-major [b,h,s,d], RoPE+dn fused
//         for q,k (each wave's 64-col span is one head; d^32 partner = nt^2).
// ---------------------------------------------------------------------------
__global__ __launch_bounds__(256) void gemm_mfma(const u16* __restrict__ A,
    const u16* __restrict__ W, float* __restrict__ oq, float* __restrict__ ok,
    float* __restrict__ ov, void* __restrict__ outAny, int K, int N, int mode,
    const void* __restrict__ cosg, const void* __restrict__ sing,
    const unsigned* __restrict__ probe)
{
  __shared__ __align__(16) u16 sA[4096];
  __shared__ __align__(16) u16 sB[4096];
  const int tid = threadIdx.x;
  const int lane = tid & 63, wave = tid >> 6;
  const int c0 = blockIdx.x*128, r0 = blockIdx.y*128;
  const int wm = wave & 1, wn = wave >> 1;
  f32x4 acc[4][4] = {};

  const int ch0 = wave*64 + lane, ch1 = 256 + wave*64 + lane;
  const u16* gA0 = A + (size_t)(r0 + (ch0>>2))*K + (ch0&3)*8;
  const u16* gA1 = A + (size_t)(r0 + (ch1>>2))*K + (ch1&3)*8;
  const u16* gB0 = W + (size_t)(c0 + (ch0>>2))*K + (ch0&3)*8;
  const u16* gB1 = W + (size_t)(c0 + (ch1>>2))*K + (ch1&3)*8;
  u16* lA0 = &sA[(wave*64)*8];  u16* lA1 = &sA[(256 + wave*64)*8];
  u16* lB0 = &sB[(wave*64)*8];  u16* lB1 = &sB[(256 + wave*64)*8];

  const u16* pA = &sA[(wm*64 + (lane&15))*32 + (lane>>4)*8];
  const u16* pB = &sB[(wn*64 + (lane&15))*32 + (lane>>4)*8];

  for (int k0 = 0; k0 < K; k0 += 32) {
    cp16(lA0, gA0 + k0); cp16(lA1, gA1 + k0);
    cp16(lB0, gB0 + k0); cp16(lB1, gB1 + k0);
    __syncthreads();
    short8 af[4], bfv[4];
    #pragma unroll
    for (int mt=0;mt<4;++mt) af[mt]  = *(const short8*)(pA + mt*512);
    #pragma unroll
    for (int nt=0;nt<4;++nt) bfv[nt] = *(const short8*)(pB + nt*512);
    #pragma unroll
    for (int mt=0;mt<4;++mt)
      #pragma unroll
      for (int nt=0;nt<4;++nt)
        acc[mt][nt] = MFMA16(af[mt], bfv[nt], acc[mt][nt]);
    __syncthreads();
  }

  const int rbase = r0 + wm*64 + (lane>>4)*4;   // + mt*16 + rg
  const int cbase = c0 + wn*64 + (lane&15);     // + nt*16
  if (mode == 0) {
    const bool f32o = probe_f32(probe);
    #pragma unroll
    for (int mt=0;mt<4;++mt)
      #pragma unroll
      for (int nt=0;nt<4;++nt)
        #pragma unroll
        for (int rg=0;rg<4;++rg){
          int r = rbase + mt*16 + rg, c = cbase + nt*16;
          float v = acc[mt][nt][rg];
          if (f32o) ((float*)outAny)[(size_t)r*N + c] = v;
          else      ((u16*)outAny)[(size_t)r*N + c] = f2u(v);
        }
  } else {
    const bool f32in = probe_f32(probe);
    const float dn = 0.3535533905932738f;  // 64^-0.25
    #pragma unroll
    for (int nt=0;nt<4;++nt){
      int cc = cbase + nt*16;
      float* dst; int H2, cl; bool isv = false;
      if (cc < 2048){ dst = oq; H2 = 32; cl = cc; }
      else if (cc < 2560){ dst = ok; H2 = 8; cl = cc - 2048; }
      else { dst = ov; H2 = 8; cl = cc - 2560; isv = true; }
      int hh = cl>>6, dd = cl&63;
      float sgn = (dd < 32) ? -1.f : 1.f;
      #pragma unroll
      for (int mt=0;mt<4;++mt)
        #pragma unroll
        for (int rg=0;rg<4;++rg){
          int r = rbase + mt*16 + rg;
          int bb = r>>11, s = r&2047;
          float v = acc[mt][nt][rg];
          if (!isv){
            float vp = acc[mt][nt^2][rg];
            size_t ci = ((size_t)bb*SEQ + s)*DH + dd;
            float cv = loadIn(cosg, ci, f32in);
            float sv = loadIn(sing, ci, f32in);
            v = (v*cv + sgn*vp*sv) * dn;
          }
          dst[(((size_t)bb*H2 + hh)*SEQ + s)*DH + dd] = v;
        }
    }
  }
}

// ---------------------------------------------------------------------------
// phi via MFMA: xp = xn[rows x 64] @ proj[256 x 64]^T, K=64.
// 64 rows/block, 4 waves x (1 row-tile x 16 col-tiles).
// mode 0: q — rowwise stab, exp, write phi
// mode 1: k pass A — rowwise max -> rmaxk
// mode 2: k pass B — exp with global stabk, write phi
// ---------------------------------------------------------------------------
__global__ __launch_bounds__(256) void phi_mfma(const float* __restrict__ xn,
    const u16* __restrict__ projb, float* __restrict__ rmaxk,
    const float* __restrict__ stabk, u16* __restrict__ phi, int mode)
{
  __shared__ __align__(16) u16 sA[64*80];
  __shared__ __align__(16) u16 sP[256*80];
  __shared__ float sq[64];
  const int tid = threadIdx.x, lane = tid & 63, wave = tid >> 6;
  const size_t row0 = (size_t)blockIdx.x * 64;

  // stage proj: 2048 short8 vectors -> [m][80] padded
  #pragma unroll
  for (int l = 0; l < 8; ++l){
    int v8 = tid + l*256;
    int off = v8*8; int m = off>>6, d = off&63;
    *(short8*)&sP[m*80 + d] = ((const short8*)projb)[v8];
  }
  // stage xn rows fp32 -> bf16 + sq partials (thread = row tid>>2, quarter tid&3)
  {
    int r = tid >> 2, qq = tid & 3;
    const float* src = xn + (row0 + r)*DH + qq*16;
    float s = 0.f;
    u16 tmp[16];
    #pragma unroll
    for (int i=0;i<16;i+=4){
      float4 v4 = *(const float4*)&src[i];
      s += v4.x*v4.x + v4.y*v4.y + v4.z*v4.z + v4.w*v4.w;
      tmp[i] = f2u(v4.x); tmp[i+1] = f2u(v4.y); tmp[i+2] = f2u(v4.z); tmp[i+3] = f2u(v4.w);
    }
    *(short8*)&sA[r*80 + qq*16]     = *(short8*)&tmp[0];
    *(short8*)&sA[r*80 + qq*16 + 8] = *(short8*)&tmp[8];
    s += __shfl_xor(s, 1, 64);
    s += __shfl_xor(s, 2, 64);
    if (qq == 0) sq[r] = 0.5f*s;
  }
  __syncthreads();

  // MFMA: wave owns rows wave*16..+15; 16 col-tiles, 2 k-steps
  f32x4 acc[16] = {};
  const u16* pA = &sA[(wave*16 + (lane&15))*80 + (lane>>4)*8];
  short8 af0 = *(const short8*)(pA);
  short8 af1 = *(const short8*)(pA + 32);
  #pragma unroll
  for (int nt=0; nt<16; ++nt){
    const u16* pB = &sP[(nt*16 + (lane&15))*80 + (lane>>4)*8];
    short8 b0 = *(const short8*)(pB);
    short8 b1 = *(const short8*)(pB + 32);
    acc[nt] = MFMA16(af0, b0, acc[nt]);
    acc[nt] = MFMA16(af1, b1, acc[nt]);
  }

  // rowwise max across 256 cols (in-reg over nt, then 16-lane butterfly)
  float mx[4];
  #pragma unroll
  for (int rg=0; rg<4; ++rg){
    float m = acc[0][rg];
    #pragma unroll
    for (int nt=1; nt<16; ++nt) m = fmaxf(m, acc[nt][rg]);
    m = fmaxf(m, __shfl_xor(m, 1, 64));
    m = fmaxf(m, __shfl_xor(m, 2, 64));
    m = fmaxf(m, __shfl_xor(m, 4, 64));
    m = fmaxf(m, __shfl_xor(m, 8, 64));
    mx[rg] = m;
  }
  const int rloc = wave*16 + (lane>>4)*4;   // + rg
  if (mode == 1){
    if ((lane & 15) == 0){
      #pragma unroll
      for (int rg=0;rg<4;++rg) rmaxk[row0 + rloc + rg] = mx[rg];
    }
    return;
  }
  float stab[4];
  if (mode == 0){
    #pragma unroll
    for (int rg=0;rg<4;++rg) stab[rg] = mx[rg];
  } else {
    float s = stabk[row0 >> 11];
    #pragma unroll
    for (int rg=0;rg<4;++rg) stab[rg] = s;
  }
  float sqr[4];
  #pragma unroll
  for (int rg=0;rg<4;++rg) sqr[rg] = sq[rloc + rg];
  #pragma unroll
  for (int nt=0;nt<16;++nt){
    #pragma unroll
    for (int rg=0;rg<4;++rg){
      float val = (__expf(fminf(acc[nt][rg] - sqr[rg] - stab[rg], 0.f)) + EPSF) * 0.0625f;
      phi[(row0 + rloc + rg)*MFEAT + nt*16 + (lane&15)] = f2u(val);
    }
  }
}

__global__ void stab_reduce_kernel(const float* __restrict__ rmaxk, float* __restrict__ stabk){
  __shared__ float red[256];
  int bk = blockIdx.x;
  float mx = -1e30f;
  for (int i = threadIdx.x; i < SEQ; i += 256) mx = fmaxf(mx, rmaxk[(size_t)bk*SEQ + i]);
  red[threadIdx.x] = mx; __syncthreads();
  for (int off=128; off>0; off>>=1){
    if ((int)threadIdx.x < off) red[threadIdx.x] = fmaxf(red[threadIdx.x], red[threadIdx.x+off]);
    __syncthreads();
  }
  if (threadIdx.x==0) stabk[bk] = red[0];
}

// ---------------------------------------------------------------------------
// kv/kz per-chunk sums: block = (bk, c); thread m accumulates phik[t,m]*v[t,:]
// ---------------------------------------------------------------------------
__global__ __launch_bounds__(256) void kvchunk_kernel(const bf16* __restrict__ phik,
    const float* __restrict__ vbuf, float* __restrict__ kv, float* __restrict__ kz)
{
  int blk = blockIdx.x; int bk = blk >> 4, c = blk & 15;
  const bf16* Kc = phik + ((size_t)bk*SEQ + c*128)*MFEAT;
  const float* Vc = vbuf + ((size_t)bk*SEQ + c*128)*DH;
  __shared__ float sV[128*64];
  for (int l=0;l<32;++l){ int idx = threadIdx.x + l*256; sV[idx] = Vc[idx]; }
  __syncthreads();
  int m = threadIdx.x;
  float acc[64] = {}; float az = 0.f;
  for (int t=0;t<128;++t){
    float ph = b2f(Kc[(size_t)t*MFEAT + m]);
    az += ph;
    const float4* vr = (const float4*)&sV[t*64];
    #pragma unroll
    for (int d4=0; d4<16; ++d4){
      float4 v4 = vr[d4];
      acc[d4*4+0] += ph*v4.x; acc[d4*4+1] += ph*v4.y;
      acc[d4*4+2] += ph*v4.z; acc[d4*4+3] += ph*v4.w;
    }
  }
  float* out = kv + (size_t)blk*MFEAT*DH + (size_t)m*DH;
  #pragma unroll
  for (int d4=0; d4<16; ++d4)
    ((float4*)out)[d4] = make_float4(acc[d4*4],acc[d4*4+1],acc[d4*4+2],acc[d4*4+3]);
  kz[(size_t)blk*MFEAT + m] = az;
}

// exclusive prefix over chunk axis
__global__ void scan_kernel(float* __restrict__ p, int inner, int nc, int total){
  int t = blockIdx.x*256 + threadIdx.x;
  if (t >= total) return;
  int outer = t / inner, rem = t - outer*inner;
  float* base = p + (size_t)outer*nc*inner + rem;
  float run = 0.f;
  for (int c=0;c<nc;++c){
    float v = base[(size_t)c*inner];
    base[(size_t)c*inner] = run;
    run += v;
  }
}

// ---------------------------------------------------------------------------
// MFMA attention: block = (b,h,chunk). 4 waves, each owns 32 rows.
// P1/P3 fused over feat chunks of 32: S += Q*K^T, O += Q*[KVpre|KZpre]
// mask S in regs -> P to LDS (bf16, stride 136); V^T staged with ones row 64.
// P2: O += P*[V|1]^T.  z (col 64) = ez+iz -> divide -> store (b,s,h,d) bf16.
// ---------------------------------------------------------------------------
__global__ __launch_bounds__(256) void attn_mfma(
    const u16* __restrict__ phiq, const u16* __restrict__ phik,
    const float* __restrict__ vbuf, const float* __restrict__ kvp,
    const float* __restrict__ kzp, u16* __restrict__ attnout)
{
  __shared__ __align__(16) u16 smem[28288];
  __shared__ float sZ[128];
  const int tid = threadIdx.x, lane = tid & 63, wave = tid >> 6;
  const int blk = blockIdx.x;
  const int c = blk & 15, h = (blk >> 4) & 31, b = blk >> 9;
  const int kvh = h >> 2;
  const u16* Q   = phiq + (((size_t)(b*NHEAD+h)*SEQ) + c*128)*MFEAT;
  const u16* Kc  = phik + (((size_t)(b*NKVH+kvh)*SEQ) + c*128)*MFEAT;
  const float* Vc  = vbuf + (((size_t)(b*NKVH+kvh)*SEQ) + c*128)*DH;
  const float* KVp = kvp + ((size_t)((b*NKVH+kvh)*NCH + c))*MFEAT*DH;
  const float* KZp = kzp + ((size_t)((b*NKVH+kvh)*NCH + c))*MFEAT;

  u16* sQ   = smem;            // [128][32]
  u16* sK   = smem + 4096;     // [128][32]
  u16* sKVT = smem + 8192;     // [80][72]  row 64 = KZpre, 65..79 unused
  u16* sP   = smem;            // [128][136]
  u16* sVT  = smem + 17408;    // [80][136] row 64 = ones, 65..79 unused

  f32x4 accS[2][8] = {};
  f32x4 accO[2][5] = {};

  const int ch0 = wave*64 + lane, ch1 = 256 + wave*64 + lane;
  const u16* gQ0 = Q  + (ch0>>2)*MFEAT + (ch0&3)*8;
  const u16* gQ1 = Q  + (ch1>>2)*MFEAT + (ch1&3)*8;
  const u16* gK0 = Kc + (ch0>>2)*MFEAT + (ch0&3)*8;
  const u16* gK1 = Kc + (ch1>>2)*MFEAT + (ch1&3)*8;
  u16* lQ0 = &sQ[(wave*64)*8];  u16* lQ1 = &sQ[(256+wave*64)*8];
  u16* lK0 = &sK[(wave*64)*8];  u16* lK1 = &sK[(256+wave*64)*8];

  for (int k0 = 0; k0 < MFEAT; k0 += 32) {
    cp16(lQ0, gQ0 + k0); cp16(lQ1, gQ1 + k0);
    cp16(lK0, gK0 + k0); cp16(lK1, gK1 + k0);
    // stage KVpre^T chunk (32 m x 64 d) + KZ row, bf16
    #pragma unroll
    for (int i=0;i<8;++i){
      int idx = tid + i*256;   // 2048
      int m = idx >> 6, d = idx & 63;
      sKVT[d*72 + m] = f2u(KVp[(size_t)(k0+m)*DH + d]);
    }
    if (tid < 32) sKVT[64*72 + tid] = f2u(KZp[k0 + tid]);
    __syncthreads();
    short8 af0, af1;
    const u16* pQ = &sQ[(wave*32 + (lane&15))*32 + (lane>>4)*8];
    af0 = *(const short8*)(pQ);
    af1 = *(const short8*)(pQ + 512);
    #pragma unroll
    for (int nt=0;nt<8;++nt){
      short8 bk = *(const short8*)&sK[(nt*16 + (lane&15))*32 + (lane>>4)*8];
      accS[0][nt] = MFMA16(af0, bk, accS[0][nt]);
      accS[1][nt] = MFMA16(af1, bk, accS[1][nt]);
    }
    #pragma unroll
    for (int nt=0;nt<5;++nt){
      short8 bi = *(const short8*)&sKVT[(nt*16 + (lane&15))*72 + (lane>>4)*8];
      accO[0][nt] = MFMA16(af0, bi, accO[0][nt]);
      accO[1][nt] = MFMA16(af1, bi, accO[1][nt]);
    }
    __syncthreads();
  }

  // mask + write P (bf16, stride 136); build V^T with ones row
  #pragma unroll
  for (int mt=0;mt<2;++mt){
    int rowb = wave*32 + mt*16 + (lane>>4)*4;
    #pragma unroll
    for (int nt=0;nt<8;++nt){
      int col = nt*16 + (lane&15);
      #pragma unroll
      for (int rg=0;rg<4;++rg){
        int row = rowb + rg;
        float v = (col <= row) ? accS[mt][nt][rg] : 0.f;
        sP[row*136 + col] = f2u(v);
      }
    }
  }
  #pragma unroll
  for (int i=0;i<32;++i){
    int idx = tid + i*256;   // 8192
    int t = idx >> 6, d = idx & 63;
    sVT[d*136 + t] = f2u(Vc[idx]);
  }
  if (tid < 128) sVT[64*136 + tid] = 0x3F80;  // bf16 1.0
  __syncthreads();

  // P2: O += P @ [V|1]
  #pragma unroll
  for (int kc=0;kc<4;++kc){
    const u16* pP = &sP[(wave*32 + (lane&15))*136 + kc*32 + (lane>>4)*8];
    short8 pa0 = *(const short8*)(pP);
    short8 pa1 = *(const short8*)(pP + 16*136);
    #pragma unroll
    for (int nt=0;nt<5;++nt){
      short8 bv = *(const short8*)&sVT[(nt*16 + (lane&15))*136 + kc*32 + (lane>>4)*8];
      accO[0][nt] = MFMA16(pa0, bv, accO[0][nt]);
      accO[1][nt] = MFMA16(pa1, bv, accO[1][nt]);
    }
  }

  // z broadcast + divide + store
  if ((lane & 15) == 0){
    #pragma unroll
    for (int mt=0;mt<2;++mt){
      int rowb = wave*32 + mt*16 + (lane>>4)*4;
      #pragma unroll
      for (int rg=0;rg<4;++rg) sZ[rowb + rg] = accO[mt][4][rg];
    }
  }
  __syncthreads();
  const int d0 = lane & 15;
  #pragma unroll
  for (int mt=0;mt<2;++mt){
    int rowb = wave*32 + mt*16 + (lane>>4)*4;
    #pragma unroll
    for (int rg=0;rg<4;++rg){
      int row = rowb + rg;
      float inv = 1.0f / (sZ[row] + EPSF);
      int sg = c*128 + row;
      size_t ob = (((size_t)b*SEQ + sg)*NHEAD + h)*DH;
      #pragma unroll
      for (int nt=0;nt<4;++nt)
        attnout[ob + nt*16 + d0] = f2u(accO[mt][nt][rg] * inv);
    }
  }
}

// ---------------------------------------------------------------------------
extern "C" void kernel_launch(void* const* d_in, const int* in_sizes, int n_in,
                              void* d_out, int out_size, void* d_ws, size_t ws_size,
                              hipStream_t stream)
{
  const void* hidden = d_in[0];
  const void* cosg   = d_in[1];
  const void* sing   = d_in[2];
  const void* Wq     = d_in[3];
  const void* Wk     = d_in[4];
  const void* Wv     = d_in[5];
  const void* Wo     = d_in[6];
  const void* proj   = d_in[7];
  const unsigned* probe = (const unsigned*)d_in[1];

  float* ws = (float*)d_ws;
  // overlays (stream-order safe):
  //   [0, 8388608): xnq (until phi_mfma q) -> then kv/kz/rmaxk/stabk
  float* xnq   = ws;                       // 8388608 f
  float* kv    = ws;                       // 4194304 f (after phi q)
  float* kz    = ws + 4194304;             //   65536 f
  float* rmaxk = ws + 4259840;             //   32768 f
  float* stabk = ws + 4292608;             //     256 f
  float* xnk   = ws + 8388608;             // 2097152 f
  float* vbuf  = ws + 10485760;            // 2097152 f
  u16*   projb = (u16*) (ws + 12582912);   //   16384 bf16
  bf16*  phiq  = (bf16*)(ws + 12591104);   // 33554432 bf16
  bf16*  phik  = (bf16*)(ws + 29368320);   //  8388608 bf16
  u16*   hb    = (u16*) (ws + 33562624);   //  8388608 bf16 (hidden; attn later)
  u16*   attn  = (u16*) (ws + 33562624);   //  (same region, after QKV gemm)
  u16*   wqkv  = (u16*) (ws + 37756928);   //  6291456 bf16
  u16*   wob   = (u16*) (ws + 37756928);   //  (same region, after QKV gemm)

  // converts: hidden + Wq|Wk|Wv (concatenated 3072x2048) + proj
  conv_kernel<<<8192, 256, 0, stream>>>(hidden, hb, probe);
  conv_kernel<<<4096, 256, 0, stream>>>(Wq, wqkv,           probe);
  conv_kernel<<<1024, 256, 0, stream>>>(Wk, wqkv + 4194304, probe);
  conv_kernel<<<1024, 256, 0, stream>>>(Wv, wqkv + 5242880, probe);
  conv_kernel<<<16,   256, 0, stream>>>(proj, projb, probe);

  // fused QKV projection + RoPE + dn (fp32 head-major out)
  gemm_mfma<<<dim3(24,32), 256, 0, stream>>>(hb, wqkv, xnq, xnk, vbuf, nullptr,
                                             2048, 3072, 1, cosg, sing, probe);
  // Wo convert (reuses wqkv region; ordered after QKV gemm)
  conv_kernel<<<4096, 256, 0, stream>>>(Wo, wob, probe);

  // phi features via MFMA
  phi_mfma<<<2048, 256, 0, stream>>>(xnq, projb, nullptr, nullptr, (u16*)phiq, 0);
  phi_mfma<<<512,  256, 0, stream>>>(xnk, projb, rmaxk, nullptr, nullptr, 1);
  stab_reduce_kernel<<<16, 256, 0, stream>>>(rmaxk, stabk);
  phi_mfma<<<512,  256, 0, stream>>>(xnk, projb, nullptr, stabk, (u16*)phik, 2);

  // chunk kv/kz states + exclusive prefix (kv overlays dead xnq region)
  kvchunk_kernel<<<256, 256, 0, stream>>>(phik, vbuf, kv, kz);
  scan_kernel<<<1024, 256, 0, stream>>>(kv, MFEAT*DH, NCH, 16*MFEAT*DH);
  scan_kernel<<<16,   256, 0, stream>>>(kz, MFEAT,    NCH, 16*MFEAT);

  // MFMA attention
  attn_mfma<<<1024, 256, 0, stream>>>((const u16*)phiq, (const u16*)phik,
                                      vbuf, kv, kz, attn);

  // output projection (out dtype follows input dtype)
  gemm_mfma<<<dim3(16,32), 256, 0, stream>>>(attn, wob, nullptr, nullptr, nullptr,
                                             d_out, 2048, 2048, 0, nullptr, nullptr, probe);
}